// Round 4
// baseline (270.837 us; speedup 1.0000x reference)
//
#include <hip/hip_runtime.h>

#define NN 2048
#define HALF 1024
#define CC 128
#define EE 65536
#define CAP 128
#define RSPLIT 4
#define RCH (HALF/RSPLIT)   /* 256 */

typedef unsigned short u16;

__device__ __forceinline__ float sigm(float v){ return 1.0f/(1.0f + __expf(-v)); }

// ---------------- K1: colsum of sigmoid(my[:1024,:1024]) (blocks 0..63) | edge bucketing (64..319)
__global__ __launch_bounds__(256) void k_prep(
    const float* __restrict__ my, const int* __restrict__ ei,
    float* __restrict__ colsum, int* __restrict__ cnt, u16* __restrict__ bucket)
{
  int b = blockIdx.x, t = threadIdx.x;
  if (b < 64) {
    int cb = b & 3, rb = b >> 2;
    int c = cb*256 + t;
    const float* p = my + (size_t)(rb*64)*NN + c;
    float s = 0.f;
    #pragma unroll 4
    for (int r=0;r<64;r++) s += sigm(p[(size_t)r*NN]);
    atomicAdd(&colsum[c], s);
  } else {
    int e = (b-64)*256 + t;
    int s = ei[e], d = ei[EE + e];
    int slot = atomicAdd(&cnt[d], 1);
    if (slot < CAP) bucket[d*CAP + slot] = (u16)s;
  }
}

// ---------------- K2: dinv = rsqrt(1 + cnt + colsum)
__global__ __launch_bounds__(256) void k_dinv(const float* __restrict__ colsum,
                                              const int* __restrict__ cnt,
                                              float* __restrict__ dinv){
  int i = blockIdx.x*256 + threadIdx.x;
  float s = 1.0f + (float)cnt[i] + (i < HALF ? colsum[i] : 0.0f);
  dinv[i] = rsqrtf(s);
}

// ---------------- fused layer aggregation:
//   blocks [0,128):    AGG[d][f] += sum_r sigm(my[r][d])*dinv[r]*dinv[d]*feat[r][f]   (dense, on-the-fly)
//   blocks [128,1152): AGG[d][f] += dinv[d]*(dinv[d]*feat[d][f] + sum_s dinv[s]*feat[s][f])  (self+sparse)
__global__ __launch_bounds__(256) void k_layer(
  const float* __restrict__ my, const float* __restrict__ feat, const float* __restrict__ dinv,
  const int* __restrict__ cnt, const u16* __restrict__ bucket, float* __restrict__ AGG)
{
  int b = blockIdx.x, t = threadIdx.x;
  if (b < 128) {
    int dtile = b >> 2;          // 0..31
    int rc = b & 3;              // 0..3
    int d = dtile*32 + (t & 31);
    int f0 = (t >> 5) * 16;      // 0,16,...,112
    float acc[16];
    #pragma unroll
    for (int j=0;j<16;j++) acc[j] = 0.f;
    int r0 = rc*RCH;
    #pragma unroll 2
    for (int r=r0; r<r0+RCH; ++r){
      float sv = sigm(my[(size_t)r*NN + d]) * dinv[r];
      const float4* fp = (const float4*)(feat + (size_t)r*CC + f0);
      float4 v0 = fp[0], v1 = fp[1], v2 = fp[2], v3 = fp[3];
      acc[0]  = fmaf(sv, v0.x, acc[0]);
      acc[1]  = fmaf(sv, v0.y, acc[1]);
      acc[2]  = fmaf(sv, v0.z, acc[2]);
      acc[3]  = fmaf(sv, v0.w, acc[3]);
      acc[4]  = fmaf(sv, v1.x, acc[4]);
      acc[5]  = fmaf(sv, v1.y, acc[5]);
      acc[6]  = fmaf(sv, v1.z, acc[6]);
      acc[7]  = fmaf(sv, v1.w, acc[7]);
      acc[8]  = fmaf(sv, v2.x, acc[8]);
      acc[9]  = fmaf(sv, v2.y, acc[9]);
      acc[10] = fmaf(sv, v2.z, acc[10]);
      acc[11] = fmaf(sv, v2.w, acc[11]);
      acc[12] = fmaf(sv, v3.x, acc[12]);
      acc[13] = fmaf(sv, v3.y, acc[13]);
      acc[14] = fmaf(sv, v3.z, acc[14]);
      acc[15] = fmaf(sv, v3.w, acc[15]);
    }
    float dd = dinv[d];
    #pragma unroll
    for (int j=0;j<16;j++)
      atomicAdd(&AGG[(size_t)d*CC + f0 + j], acc[j]*dd);
  } else {
    int idx = b - 128;
    int d = idx*2 + (t>>7), f = t & 127;
    float dd = dinv[d];
    float acc = dd * feat[(size_t)d*CC + f];
    int m = cnt[d]; m = m > CAP ? CAP : m;
    const u16* bk = bucket + d*CAP;
    for (int j=0;j<m;j++){
      int s = bk[j];
      acc = fmaf(dinv[s], feat[(size_t)s*CC + f], acc);
    }
    atomicAdd(&AGG[(size_t)d*CC + f], dd*acc);
  }
}

// ---------------- hidden = relu(AGG @ W1 + b1)
__global__ __launch_bounds__(256) void k_hidden(
  const float* __restrict__ AGG, const float* __restrict__ W1, const float* __restrict__ b1,
  float* __restrict__ hid)
{
  __shared__ float la[2][CC];
  int t = threadIdx.x;
  int rloc = t >> 7, k = t & 127;
  int row = blockIdx.x*2 + rloc;
  la[rloc][k] = AGG[(size_t)row*CC + k];
  __syncthreads();
  int f = k;
  float acc = b1[f];
  const float* ar = la[rloc];
  #pragma unroll 8
  for (int kk=0;kk<CC;kk++) acc = fmaf(ar[kk], W1[kk*CC + f], acc);
  hid[(size_t)row*CC + f] = acc > 0.f ? acc : 0.f;
}

// ---------------- z = AGG @ [Wmu|Wls] + [bmu|bls] -> out (f32, concatenated)
__global__ __launch_bounds__(256) void k_z(
  const float* __restrict__ AGG, const float* __restrict__ Wmu, const float* __restrict__ bmu,
  const float* __restrict__ Wls, const float* __restrict__ bls,
  float* __restrict__ out)
{
  __shared__ float la[2][CC];
  int t = threadIdx.x;
  int rloc = t >> 7, k = t & 127;
  int row = blockIdx.x*2 + rloc;
  la[rloc][k] = AGG[(size_t)row*CC + k];
  __syncthreads();
  int f = k;
  const float* ar = la[rloc];
  if (f < 64) {
    float acc = bmu[f];
    #pragma unroll 8
    for (int kk=0;kk<CC;kk++) acc = fmaf(ar[kk], Wmu[kk*64 + f], acc);
    out[(size_t)row*64 + f] = acc;
  } else {
    int g = f - 64;
    float acc = bls[g];
    #pragma unroll 8
    for (int kk=0;kk<CC;kk++) acc = fmaf(ar[kk], Wls[kk*64 + g], acc);
    out[(size_t)NN*64 + (size_t)row*64 + g] = acc;
  }
}

extern "C" void kernel_launch(void* const* d_in, const int* in_sizes, int n_in,
                              void* d_out, int out_size, void* d_ws, size_t ws_size,
                              hipStream_t stream)
{
  (void)in_sizes; (void)n_in; (void)out_size; (void)ws_size;
  const float* x   = (const float*)d_in[0];
  const float* my  = (const float*)d_in[1];
  const float* W1  = (const float*)d_in[2];
  const float* b1  = (const float*)d_in[3];
  const float* Wmu = (const float*)d_in[4];
  const float* bmu = (const float*)d_in[5];
  const float* Wls = (const float*)d_in[6];
  const float* bls = (const float*)d_in[7];
  const int*   ei  = (const int*)d_in[8];
  float* out = (float*)d_out;
  char* ws = (char*)d_ws;

  // ws layout — zeroed prefix first (colsum, cnt, AGG1, AGG2), total 3.5 MB
  float* colsum = (float*)(ws + 0);        //    4096 B  (memset 0)
  int*   cnt    = (int*)  (ws + 4096);     //    8192 B  (memset 0)
  float* AGG1   = (float*)(ws + 12288);    // 1048576 B  (memset 0)
  float* AGG2   = (float*)(ws + 1060864);  // 1048576 B  (memset 0)
  float* dinv   = (float*)(ws + 2109440);  //    8192 B
  u16*   bucket = (u16*)  (ws + 2117632);  //  524288 B
  float* hid    = (float*)(ws + 2641920);  // 1048576 B

  hipMemsetAsync(ws, 0, 2109440, stream);
  k_prep <<<320,  256, 0, stream>>>(my, ei, colsum, cnt, bucket);
  k_dinv <<<8,    256, 0, stream>>>(colsum, cnt, dinv);
  k_layer<<<1152, 256, 0, stream>>>(my, x,   dinv, cnt, bucket, AGG1);
  k_hidden<<<1024,256, 0, stream>>>(AGG1, W1, b1, hid);
  k_layer<<<1152, 256, 0, stream>>>(my, hid, dinv, cnt, bucket, AGG2);
  k_z    <<<1024, 256, 0, stream>>>(AGG2, Wmu, bmu, Wls, bls, out);
}

// Round 5
// 178.903 us; speedup vs baseline: 1.5139x; 1.5139x over previous
//
#include <hip/hip_runtime.h>

#define NN 2048
#define HALF 1024
#define CC 128
#define EE 65536
#define CAP 128

typedef unsigned short u16;

__device__ __forceinline__ float sigm(float v){ return 1.0f/(1.0f + __expf(-v)); }

// ---------------- K1: blocks [0,128): SpRaw[r][c]=sigm(my[r][c]) + colsum (row-major, coalesced)
//                    blocks [128,384): edge bucketing
__global__ __launch_bounds__(256) void k_prep(
    const float* __restrict__ my, const int* __restrict__ ei,
    float* __restrict__ SpRaw, float* __restrict__ colsum,
    int* __restrict__ cnt, u16* __restrict__ bucket)
{
  int b = blockIdx.x, t = threadIdx.x;
  if (b < 128) {
    int c0 = t*4;
    float cs0=0.f, cs1=0.f, cs2=0.f, cs3=0.f;
    #pragma unroll 2
    for (int rr=0; rr<8; ++rr){
      int r = b*8 + rr;
      float4 v = *(const float4*)(my + (size_t)r*NN + c0);
      float s0=sigm(v.x), s1=sigm(v.y), s2=sigm(v.z), s3=sigm(v.w);
      *(float4*)(SpRaw + (size_t)r*HALF + c0) = make_float4(s0,s1,s2,s3);
      cs0+=s0; cs1+=s1; cs2+=s2; cs3+=s3;
    }
    atomicAdd(&colsum[c0+0], cs0);
    atomicAdd(&colsum[c0+1], cs1);
    atomicAdd(&colsum[c0+2], cs2);
    atomicAdd(&colsum[c0+3], cs3);
  } else {
    int e = (b-128)*256 + t;
    int s = ei[e], d = ei[EE + e];
    int slot = atomicAdd(&cnt[d], 1);
    if (slot < CAP) bucket[d*CAP + slot] = (u16)s;
  }
}

// ---------------- K2: dinv = rsqrt(1 + cnt + colsum)
__global__ __launch_bounds__(256) void k_dinv(const float* __restrict__ colsum,
                                              const int* __restrict__ cnt,
                                              float* __restrict__ dinv){
  int i = blockIdx.x*256 + threadIdx.x;
  float s = 1.0f + (float)cnt[i] + (i < HALF ? colsum[i] : 0.0f);
  dinv[i] = rsqrtf(s);
}

// ---------------- fused layer:
//  blocks [0,256):    dense  AGG[d][f] += dinv[d] * sum_r SpRaw[r][d]*dinv[r]*F[r][f]
//  blocks [256,1280): sparse AGG[d][f] += dinv[d]*(dinv[d]*F[d][f] + sum_s dinv[s]*F[s][f])
__global__ __launch_bounds__(256) void k_layer(
  const float* __restrict__ SpRaw, const float* __restrict__ F, const float* __restrict__ dinv,
  const int* __restrict__ cnt, const u16* __restrict__ bucket, float* __restrict__ AGG)
{
  int b = blockIdx.x, t = threadIdx.x;
  if (b < 256) {
    int f = t & 127, half = t >> 7;
    int dbase = (b>>2)*16 + half*8;
    int r0 = (b&3)*256;
    float acc[8];
    #pragma unroll
    for (int j=0;j<8;j++) acc[j] = 0.f;
    #pragma unroll 4
    for (int r=r0; r<r0+256; ++r){
      float fv = F[(size_t)r*CC + f] * dinv[r];
      const float4* sp4 = (const float4*)(SpRaw + (size_t)r*HALF + dbase);
      float4 s0 = sp4[0], s1 = sp4[1];
      acc[0] = fmaf(s0.x, fv, acc[0]);
      acc[1] = fmaf(s0.y, fv, acc[1]);
      acc[2] = fmaf(s0.z, fv, acc[2]);
      acc[3] = fmaf(s0.w, fv, acc[3]);
      acc[4] = fmaf(s1.x, fv, acc[4]);
      acc[5] = fmaf(s1.y, fv, acc[5]);
      acc[6] = fmaf(s1.z, fv, acc[6]);
      acc[7] = fmaf(s1.w, fv, acc[7]);
    }
    #pragma unroll
    for (int j=0;j<8;j++)
      atomicAdd(&AGG[(size_t)(dbase+j)*CC + f], acc[j]*dinv[dbase+j]);
  } else {
    int idx = b - 256;
    int d = idx*2 + (t>>7), f = t & 127;
    float dd = dinv[d];
    float acc = dd * F[(size_t)d*CC + f];
    int m = cnt[d]; m = m > CAP ? CAP : m;
    const u16* bk = bucket + d*CAP;
    for (int j=0;j<m;j++){
      int s = bk[j];
      acc = fmaf(dinv[s], F[(size_t)s*CC + f], acc);
    }
    atomicAdd(&AGG[(size_t)d*CC + f], dd*acc);
  }
}

// ---------------- hidden = relu(AGG @ W1 + b1)   (256 blocks x 8 rows)
__global__ __launch_bounds__(256) void k_hidden(
  const float* __restrict__ AGG, const float* __restrict__ W1, const float* __restrict__ b1,
  float* __restrict__ hid)
{
  __shared__ float la[8][CC];
  int t = threadIdx.x;
  int row0 = blockIdx.x*8;
  #pragma unroll
  for (int i=0;i<4;i++){
    int idx = i*256 + t;
    la[idx>>7][idx&127] = AGG[(size_t)row0*CC + idx];
  }
  __syncthreads();
  int f = t & 127, rh = t >> 7;        // rh: 0 -> rows 0..3, 1 -> rows 4..7
  float acc[4];
  float bb = b1[f];
  #pragma unroll
  for (int i=0;i<4;i++) acc[i] = bb;
  #pragma unroll 4
  for (int kk=0;kk<CC;kk++){
    float w = W1[kk*CC + f];
    #pragma unroll
    for (int i=0;i<4;i++) acc[i] = fmaf(la[rh*4+i][kk], w, acc[i]);
  }
  #pragma unroll
  for (int i=0;i<4;i++){
    float v = acc[i];
    hid[(size_t)(row0 + rh*4 + i)*CC + f] = v > 0.f ? v : 0.f;
  }
}

// ---------------- z = AGG @ [Wmu|Wls] + [bmu|bls] -> out (concat)   (256 blocks x 8 rows)
__global__ __launch_bounds__(256) void k_z(
  const float* __restrict__ AGG, const float* __restrict__ Wmu, const float* __restrict__ bmu,
  const float* __restrict__ Wls, const float* __restrict__ bls,
  float* __restrict__ out)
{
  __shared__ float la[8][CC];
  int t = threadIdx.x;
  int row0 = blockIdx.x*8;
  #pragma unroll
  for (int i=0;i<4;i++){
    int idx = i*256 + t;
    la[idx>>7][idx&127] = AGG[(size_t)row0*CC + idx];
  }
  __syncthreads();
  int f = t & 127, rh = t >> 7;
  const float* W = (f < 64) ? Wmu : Wls;
  int g = f & 63;
  float bb = (f < 64) ? bmu[g] : bls[g];
  size_t obase = (f < 64) ? 0 : (size_t)NN*64;
  float acc[4];
  #pragma unroll
  for (int i=0;i<4;i++) acc[i] = bb;
  #pragma unroll 4
  for (int kk=0;kk<CC;kk++){
    float w = W[kk*64 + g];
    #pragma unroll
    for (int i=0;i<4;i++) acc[i] = fmaf(la[rh*4+i][kk], w, acc[i]);
  }
  #pragma unroll
  for (int i=0;i<4;i++)
    out[obase + (size_t)(row0 + rh*4 + i)*64 + g] = acc[i];
}

extern "C" void kernel_launch(void* const* d_in, const int* in_sizes, int n_in,
                              void* d_out, int out_size, void* d_ws, size_t ws_size,
                              hipStream_t stream)
{
  (void)in_sizes; (void)n_in; (void)out_size; (void)ws_size;
  const float* x   = (const float*)d_in[0];
  const float* my  = (const float*)d_in[1];
  const float* W1  = (const float*)d_in[2];
  const float* b1  = (const float*)d_in[3];
  const float* Wmu = (const float*)d_in[4];
  const float* bmu = (const float*)d_in[5];
  const float* Wls = (const float*)d_in[6];
  const float* bls = (const float*)d_in[7];
  const int*   ei  = (const int*)d_in[8];
  float* out = (float*)d_out;
  char* ws = (char*)d_ws;

  // ws layout — zeroed prefix first (colsum, cnt, AGG1, AGG2); total 6.5 MB
  float* colsum = (float*)(ws + 0);        //    4096 B  (memset 0)
  int*   cnt    = (int*)  (ws + 4096);     //    8192 B  (memset 0)
  float* AGG1   = (float*)(ws + 12288);    // 1048576 B  (memset 0)
  float* AGG2   = (float*)(ws + 1060864);  // 1048576 B  (memset 0)
  float* dinv   = (float*)(ws + 2109440);  //    8192 B
  u16*   bucket = (u16*)  (ws + 2117632);  //  524288 B
  float* SpRaw  = (float*)(ws + 2641920);  // 4194304 B
  float* hid    = (float*)(ws + 6836224);  // 1048576 B

  hipMemsetAsync(ws, 0, 2109440, stream);
  k_prep  <<<384,  256, 0, stream>>>(my, ei, SpRaw, colsum, cnt, bucket);
  k_dinv  <<<8,    256, 0, stream>>>(colsum, cnt, dinv);
  k_layer <<<1280, 256, 0, stream>>>(SpRaw, x,   dinv, cnt, bucket, AGG1);
  k_hidden<<<256,  256, 0, stream>>>(AGG1, W1, b1, hid);
  k_layer <<<1280, 256, 0, stream>>>(SpRaw, hid, dinv, cnt, bucket, AGG2);
  k_z     <<<256,  256, 0, stream>>>(AGG2, Wmu, bmu, Wls, bls, out);
}